// Round 6
// baseline (201.420 us; speedup 1.0000x reference)
//
#include <hip/hip_runtime.h>
#include <math.h>

// CRITICAL: ban FMA contraction file-wide. 1-ulp iou shifts flip near-tie
// argmaxes vs numpy's correctly-rounded ref (rounds 2-4, absmax 69).
#pragma clang fp contract(off)

// Shapes: B=64, N=100, A=8732.
// Out layout (f32 flat): [0,BA) labels | [BA,5BA) boxes | [5BA,6BA) mask
//
// ROUND 6: span-factor fix with the r4 inner loop kept byte-identical.
// r2/r4 both sit at 63us = 31.5us/task x span 2.0 (8960 wave-tasks on 8192
// resident wave slots; occupancy 45-48% = full round + 9% round). r5's
// fine-split failed by breaking wave-uniform loads (FETCH 2x) and spamming
// per-lane atomics into read-hot lines (WRITE 3x). This round: grid = 2048
// resident blocks exactly; 8768 tiles (64 anchors each, 137/b) assigned
// tile-ALIGNED to blocks (4-5 tiles); the block's 4 waves split its tiles
// at 25-gt chunk granularity (16-20 chunk-micros -> 4-5 per wave; span
// 1.25T vs 2.0T). Segments are 25-aligned so the static passChunk<25>
// bodies and replay survive unchanged. Partial row results (exact-iou
// packed (bits<<32)|(NN-bi), r3/r5-validated ordering: max iou then
// smallest n = numpy first-max) merge across the block's waves via LDS
// atomicMax u64 (block-local, no global traffic); one coalesced decode
// writes out_slot in the proven bi|POS_BIT encoding. Column path, prior,
// encode, scatter: unchanged from r4.
//
// colmax u64[B*N]: init by prior (prior_bits<<32 | 0: low=0 loses ties to
// genuine submissions low>=1), atomicMax'd by iou, consumed by encode
// (fused, colmax in ws) or scatter (fallback, colmax in out's boxes region).
// tab f32[B*N*8] {gx,gy,gz,gw, ag, scurf, 0,0}: in out's boxes region after
// the fallback-colmax slot (only read by iou; encode overwrites last).

#define AA 8732
#define NN 100
#define BB 64
#define TPB 137               // tiles per b = ceil(8732/64)
#define NTILES (BB * TPB)     // 8768
#define NBLK 2048             // exact resident fit (8 blocks/CU, 256 thr)
#define NTILE 35              // ceil(AA/256) for encode grid
#define EPS_F 1e-6f
#define OVR_FLAG 0x10000
#define POS_BIT  0x8000
// qa = inter*v_rcp(uni): rel err <= ~1.8e-7. DEFL=1-5e-7 deflation makes all
// filters rigorous one-sided bounds (HW-validated rounds 8/10/11).
#define DEFL 0.9999995f
#define RT_SEED 1e-38f        // > 0: (qa >= rt) implies qa > 0 (validated r3)

__constant__ int FM_SIZE[6] = {38, 19, 10, 5, 3, 1};
__constant__ int FM_NF[6]   = {4, 6, 6, 6, 4, 4};
__constant__ int FM_OFF[6]  = {0, 5776, 7942, 8542, 8692, 8728};

__device__ __forceinline__ void geom(const float4 axy, const float4 g,
                                     float area_a, float ag,
                                     float& inter, float& uni) {
    float ltx = fmaxf(axy.x, g.x);
    float lty = fmaxf(axy.y, g.y);
    float rbx = fminf(axy.z, g.z);
    float rby = fminf(axy.w, g.w);
    float w = fmaxf(rbx - ltx, 0.0f);
    float h = fmaxf(rby - lty, 0.0f);
    inter = w * h;
    uni = area_a + ag - inter;       // uni >= max area > 0 always
}

// ---------------------------------------------------------------------------
// Prior: per (b,n), rcp-approx max IoU over the <=30 center-cell anchors,
// deflated => SAFE lower bound of the column max. Writes colmax init AND the
// 32B record table {g, ag, scurf_seed}.
// ---------------------------------------------------------------------------
__global__ void prior_kernel(const float4* __restrict__ gt_boxes,
                             const float4* __restrict__ anchors_xyxy,
                             unsigned long long* __restrict__ colmax,
                             float4* __restrict__ tab4) {
    const int b = blockIdx.x;
    const int n = threadIdx.x;
    if (n >= NN) return;
    float4 g = gt_boxes[b * NN + n];
    float ag = (g.z - g.x) * (g.w - g.y);
    float cx = (g.x + g.z) * 0.5f;
    float cy = (g.y + g.w) * 0.5f;
    float best = 0.0f;
    for (int f = 0; f < 6; f++) {
        int s = FM_SIZE[f];
        int j = (int)(cx * (float)s); j = j < s - 1 ? j : s - 1;
        int i = (int)(cy * (float)s); i = i < s - 1 ? i : s - 1;
        int base = FM_OFF[f] + (i * s + j) * FM_NF[f];
        for (int k = 0; k < FM_NF[f]; k++) {
            float4 an = anchors_xyxy[base + k];
            float area_a = (an.z - an.x) * (an.w - an.y);
            float inter, uni;
            geom(an, g, area_a, ag, inter, uni);
            best = fmaxf(best, inter * __builtin_amdgcn_rcpf(uni));
        }
    }
    float defl = best * DEFL;        // <= colM*(1-3.2e-7): safe lower bound
    colmax[b * NN + n] = ((unsigned long long)__float_as_uint(defl)) << 32;
    tab4[(b * NN + n) * 2]     = g;
    tab4[(b * NN + n) * 2 + 1] = make_float4(ag, defl, 0.0f, 0.0f);
}

// ---------------------------------------------------------------------------
// 25-gt chunk [N0,N1): r4's proven body verbatim (wave-uniform table reads,
// running deflated rt, record mask, in-loop __any trigger + butterfly +
// lane0 submit with global scurf warm-up — rare after prior priming).
// ---------------------------------------------------------------------------
template <int N0, int N1>
__device__ __forceinline__ void passChunk(
        const float4 axy, const float area_a, const unsigned lowkey,
        const int lane,
        const float4* __restrict__ tb,              // 2 float4 per gt record
        float* tb_at,                               // same row, atomic target
        unsigned long long* __restrict__ cm,
        float& rt, unsigned& rm)
{
    #pragma unroll 5
    for (int n = N0; n < N1; n++) {
        float4 g = tb[n * 2];
        float4 q = tb[n * 2 + 1];  // .x=ag, .y=scurf (stale = superset, safe)
        float inter, uni;
        geom(axy, g, area_a, q.x, inter, uni);
        float qa = inter * __builtin_amdgcn_rcpf(uni);
        bool r = (qa >= rt);                         // row near-record
        rt = fmaxf(rt, qa * DEFL);
        rm |= (r ? 1u : 0u) << (n - N0);
        if (__any((int)(qa >= q.y))) {               // column trigger (rare)
            float iou = inter / uni;                 // exact IEEE == numpy
            bool cc = (qa >= q.y);
            unsigned long long p = cc
                ? ((((unsigned long long)__float_as_uint(iou)) << 32) |
                   (unsigned long long)lowkey) : 0ull;
            #pragma unroll
            for (int off = 32; off > 0; off >>= 1) {
                unsigned long long o = __shfl_xor(p, off);
                p = o > p ? o : p;
            }
            if (lane == 0 && p != 0ull) {
                atomicMax(cm + n, p);
                atomicMax((unsigned*)(tb_at + n * 8 + 5),    // scurf warm-up
                    __float_as_uint(
                        __uint_as_float((unsigned)(p >> 32)) * DEFL));
            }
        }
    }
}

// ---------------------------------------------------------------------------
// Resident-tile iou pass. 2048 blocks x 256 (launch_bounds(256,8): all
// blocks co-resident, one scheduling round). Block b0 owns tiles
// [b0*137>>5, (b0+1)*137>>5) — 4 or 5 tiles, tile-ALIGNED (no cross-block
// row splits). Its 4 waves partition the block's 16-20 25-gt chunk-micros
// into 4-5 each; a wave's segment within one tile is a static chunk range
// [c_lo, c_hi) with wave-uniform guards. Per segment: r4 body + replay vs
// the segment's partial rt; exact-iou packed partial merged into the
// block's LDS table (atomicMax u64). Final phase decodes LDS -> out_slot.
// Pad rows (a>=AA) clamp to anchor AA-1: genuine clone values, idempotent
// under max; decode skips them.
// ---------------------------------------------------------------------------
__global__ __launch_bounds__(256, 8) void iou_tile_kernel(
        const float4* __restrict__ anchors_xyxy,    // A
        const float4* __restrict__ tab_ro,          // B*N records (read)
        float* tab_at,                              // same base (atomics)
        unsigned long long* __restrict__ colmax,    // B*N packed, prior-init
        int* __restrict__ out_slot)                 // -> out[5BA..6BA)
{
    const int b0   = blockIdx.x;
    const int tid  = threadIdx.x;
    const int lane = tid & 63;
    const int w    = tid >> 6;
    const int t_lo = (b0 * TPB) >> 5;               // NTILES/NBLK = 137/32
    const int t_hi = ((b0 + 1) * TPB) >> 5;
    const int ntl  = t_hi - t_lo;                   // 4 or 5
    const int nm   = ntl * 4;                       // 25-gt micros in block
    const int u_lo = (w * nm) >> 2;                 // wave's micro range
    const int u_hi = ((w + 1) * nm) >> 2;

    __shared__ unsigned long long lmax[5 * 64];     // [tile][lane] packed
    for (int i = tid; i < ntl * 64; i += 256) lmax[i] = 0ull;
    __syncthreads();

    int m = u_lo;
    while (m < u_hi) {
        const int ts   = m >> 2;                    // local tile 0..4
        const int c_lo = m & 3;
        const int mend = min(u_hi, (ts + 1) * 4);
        const int c_hi = c_lo + (mend - m);         // chunks [c_lo, c_hi)
        const int tt   = t_lo + ts;
        const int b    = tt / TPB;                  // magic mul
        const int trel = tt - b * TPB;
        const int a    = trel * 64 + lane;
        const int ac   = a < AA ? a : (AA - 1);
        const float4 axy = anchors_xyxy[ac];
        const float area_a = (axy.z - axy.x) * (axy.w - axy.y);
        const unsigned lowkey = (unsigned)(AA - ac);
        const float4* __restrict__ tb = tab_ro + (size_t)b * NN * 2;
        float* tbat = tab_at + (size_t)b * NN * 8;
        unsigned long long* cmx = colmax + (size_t)b * NN;

        // -------- Phase A: static 25-chunks gated by uniform range --------
        float rt = RT_SEED;        // (qa >= rt) implies qa > 0
        unsigned rm0 = 0, rm1 = 0, rm2 = 0, rm3 = 0;
        if (c_lo == 0)             passChunk< 0, 25>(axy, area_a, lowkey,
                                       lane, tb, tbat, cmx, rt, rm0);
        if (c_lo <= 1 && c_hi > 1) passChunk<25, 50>(axy, area_a, lowkey,
                                       lane, tb, tbat, cmx, rt, rm1);
        if (c_lo <= 2 && c_hi > 2) passChunk<50, 75>(axy, area_a, lowkey,
                                       lane, tb, tbat, cmx, rt, rm2);
        if (c_hi > 3)              passChunk<75,100>(axy, area_a, lowkey,
                                       lane, tb, tbat, cmx, rt, rm3);

        // -------- Phase B: replay own records vs segment-final rt ---------
        float bv = 0.0f;   // default (0, bi=0) == numpy all-zero row
        int bi = 0;
        unsigned rms[4] = {rm0, rm1, rm2, rm3};
        #pragma unroll
        for (int h = 0; h < 4; h++) {
            unsigned mm = rms[h];
            const int nb = h * 25;
            while (mm) {
                int n = __builtin_ctz(mm) + nb;
                mm &= mm - 1;
                float inter, uni;
                geom(axy, tb[n * 2], area_a, tb[n * 2 + 1].x, inter, uni);
                float qa = inter * __builtin_amdgcn_rcpf(uni);
                if (qa >= rt) {                      // final-threshold re-test
                    float iou = inter / uni;         // exact IEEE == numpy
                    if (iou > bv) { bv = iou; bi = n; } // strict >: first max
                }
            }
        }

        // -------- merge partial into block-local LDS (exact bits) ---------
        unsigned long long k =
            (((unsigned long long)__float_as_uint(bv)) << 32) |
            (unsigned long long)(unsigned)(NN - bi);
        atomicMax(&lmax[ts * 64 + lane], k);

        m = mend;
    }
    __syncthreads();

    // -------- decode merged rows -> out_slot (proven encoding) ------------
    for (int i = tid; i < ntl * 64; i += 256) {
        const int ts = i >> 6, ln = i & 63;
        const int tt = t_lo + ts;
        const int b  = tt / TPB;
        const int trel = tt - b * TPB;
        const int a  = trel * 64 + ln;
        if (a < AA) {
            unsigned long long k = lmax[i];
            float fbv = __uint_as_float((unsigned)(k >> 32));
            int   fbi = NN - (int)(k & 0xFFFFFFFFull);
            out_slot[(size_t)b * AA + a] = fbi | (fbv > 0.5f ? POS_BIT : 0);
        }
    }
}

// ---------------------------------------------------------------------------
// FUSED encode: scatter folded in via LDS override table (needs colmax in
// ws, outside the boxes region encode overwrites). ovr[rel] = max n whose
// column winner is anchor abase+rel (atomicMax == np last-n-wins). low==0
// prior sentinel rejected by the low>=1 guard.
// ---------------------------------------------------------------------------
__global__ __launch_bounds__(256) void encode_fused_kernel(
        const int* __restrict__ gt_labels,
        const float4* __restrict__ gt_boxes,        // xyxy
        const float4* __restrict__ anchors_cxcywh,
        const unsigned long long* __restrict__ colmax,
        float* __restrict__ out)
{
    const int b = blockIdx.y;
    const int tid = threadIdx.x;
    const int abase = blockIdx.x * 256;

    __shared__ float4 sg[NN];
    __shared__ int    slab[NN];
    __shared__ int    ovr[256];

    ovr[tid] = -1;
    if (tid < NN) {
        sg[tid]   = gt_boxes[b * NN + tid];
        slab[tid] = gt_labels[b * NN + tid];
    }
    __syncthreads();
    if (tid < NN) {
        unsigned long long v = colmax[b * NN + tid];
        unsigned low = (unsigned)(v & 0xFFFFFFFFull);
        if (low >= 1u && low <= (unsigned)AA) {
            int rel = (AA - (int)low) - abase;       // column-winner anchor
            if (rel >= 0 && rel < 256) atomicMax(&ovr[rel], tid);
        }
    }
    __syncthreads();

    const int a = abase + tid;
    if (a >= AA) return;

    const size_t BA = (size_t)BB * AA;
    const size_t base = (size_t)b * AA + a;

    int s = ((const int*)(out + 5 * BA))[base];
    int o = ovr[tid];

    int idx; bool pos;
    if (o >= 0) { idx = o;          pos = true; }
    else        { idx = s & 0x7FFF; pos = (s & POS_BIT) != 0; }

    const float4 g = sg[idx];
    const float gcx = (g.x + g.z) * 0.5f;
    const float gcy = (g.y + g.w) * 0.5f;
    const float gw  = g.z - g.x;
    const float gh  = g.w - g.y;

    const float4 anc = anchors_cxcywh[a];
    const float ecx = (gcx - anc.x) / anc.z;
    const float ecy = (gcy - anc.y) / anc.w;
    const float ew  = logf((gw + EPS_F) / (anc.z + EPS_F));
    const float eh  = logf((gh + EPS_F) / (anc.w + EPS_F));

    out[base] = pos ? (float)slab[idx] : 0.0f;                   // labels
    ((float4*)(out + BA))[base] = make_float4(ecx, ecy, ew, eh); // boxes
    out[5 * BA + base] = pos ? 1.0f : 0.0f;                      // mask
}

// ---------------------------------------------------------------------------
// Fallback scatter + encode (HW-proven): used when ws_size < 51,200 B and
// colmax must alias out's boxes region (consumed before encode overwrites).
// ---------------------------------------------------------------------------
__global__ void scatter_kernel(const unsigned long long* __restrict__ colmax,
                               int* __restrict__ out_slot) {
    const int b = blockIdx.x;
    const int n = threadIdx.x;
    if (n < NN) {
        unsigned long long v = colmax[b * NN + n];
        unsigned low = (unsigned)(v & 0xFFFFFFFFull);
        if (low >= 1u && low <= (unsigned)AA) {
            int idx = AA - (int)low;
            atomicMax(&out_slot[(size_t)b * AA + idx], OVR_FLAG + n);
        }
    }
}

__global__ __launch_bounds__(256) void encode_kernel(
        const int* __restrict__ gt_labels,
        const float4* __restrict__ gt_boxes,        // xyxy
        const float4* __restrict__ anchors_cxcywh,
        float* __restrict__ out)
{
    const int b = blockIdx.y;
    const int tid = threadIdx.x;
    const int a = blockIdx.x * 256 + tid;

    __shared__ float4 sg[NN];
    __shared__ int    slab[NN];
    if (tid < NN) {
        sg[tid]   = gt_boxes[b * NN + tid];
        slab[tid] = gt_labels[b * NN + tid];
    }
    __syncthreads();
    if (a >= AA) return;

    const size_t BA = (size_t)BB * AA;
    const size_t base = (size_t)b * AA + a;

    int s = ((const int*)(out + 5 * BA))[base];

    int idx; bool pos;
    if (s >= OVR_FLAG) { idx = s - OVR_FLAG;  pos = true; }
    else               { idx = s & 0x7FFF;    pos = (s & POS_BIT) != 0; }

    const float4 g = sg[idx];
    const float gcx = (g.x + g.z) * 0.5f;
    const float gcy = (g.y + g.w) * 0.5f;
    const float gw  = g.z - g.x;
    const float gh  = g.w - g.y;

    const float4 anc = anchors_cxcywh[a];
    const float ecx = (gcx - anc.x) / anc.z;
    const float ecy = (gcy - anc.y) / anc.w;
    const float ew  = logf((gw + EPS_F) / (anc.z + EPS_F));
    const float eh  = logf((gh + EPS_F) / (anc.w + EPS_F));

    out[base] = pos ? (float)slab[idx] : 0.0f;                   // labels
    ((float4*)(out + BA))[base] = make_float4(ecx, ecy, ew, eh); // boxes
    out[5 * BA + base] = pos ? 1.0f : 0.0f;                      // mask
}

extern "C" void kernel_launch(void* const* d_in, const int* in_sizes, int n_in,
                              void* d_out, int out_size, void* d_ws, size_t ws_size,
                              hipStream_t stream) {
    const int*    gt_labels    = (const int*)d_in[0];
    const float4* gt_boxes     = (const float4*)d_in[1];
    const float4* anchors_cxcy = (const float4*)d_in[2];
    const float4* anchors_xyxy = (const float4*)d_in[3];
    float* out = (float*)d_out;

    const size_t BA = (size_t)BB * AA;
    int* slot = (int*)(out + 5 * BA);

    // Fused path needs colmax (B*N u64 = 51,200 B) outside out (engaged and
    // proven in round 2: ws >= 51,200). The 32B record table lives in out's
    // boxes region AFTER the fallback-colmax slot (only read by iou; encode
    // overwrites the boxes region last). Offsets identical in both paths.
    const bool fused = (ws_size >= (size_t)(BB * NN * 8));
    unsigned long long* colmax = fused
        ? (unsigned long long*)d_ws                  // 8B-aligned ws
        : (unsigned long long*)(out + BA);           // boxes region (proven)
    float* tabf = out + BA + (size_t)BB * NN * 2;    // skip 51,200 B
    float4* tab4 = (float4*)tabf;

    prior_kernel<<<BB, 128, 0, stream>>>(gt_boxes, anchors_xyxy, colmax, tab4);

    iou_tile_kernel<<<NBLK, 256, 0, stream>>>(anchors_xyxy, tab4, tabf,
                                              colmax, slot);

    dim3 egrid(NTILE, BB);    // (35, 64)
    if (fused) {
        encode_fused_kernel<<<egrid, 256, 0, stream>>>(gt_labels, gt_boxes,
                                                       anchors_cxcy, colmax,
                                                       out);
    } else {
        scatter_kernel<<<BB, 128, 0, stream>>>(colmax, slot);
        encode_kernel<<<egrid, 256, 0, stream>>>(gt_labels, gt_boxes,
                                                 anchors_cxcy, out);
    }
}